// Round 9
// baseline (326.321 us; speedup 1.0000x reference)
//
#include <hip/hip_runtime.h>
#include <math.h>

// Problem constants
#define NB   4
#define SEQ  1024
#define DMOD 512
#define NHD  8
#define DK   64

typedef unsigned short ushort_t;
typedef __attribute__((ext_vector_type(8))) short bf16x8;
typedef __attribute__((ext_vector_type(4))) float f32x4;

// ---------------- workspace layout (bytes) ----------------
#define XQ_OFF   1024
#define XK_OFF   (XQ_OFF + 4194304)
#define XV_OFF   (XK_OFF + 4194304)
#define WQ_OFF   (XV_OFF + 4194304)
#define WK_OFF   (WQ_OFF + 524288)
#define WV_OFF   (WK_OFF + 524288)
#define WF_OFF   (WV_OFF + 524288)
#define QBF_OFF  (WF_OFF + 524288)
#define KBF_OFF  (QBF_OFF + 4194304)
#define VT_OFF   (KBF_OFF + 12582912)
// aliases (stream-ordered safe):
#define POSBF_OFF XQ_OFF  // 4MB packed-bf16 pos; written by setup, read by
                          // fused_attn, overwritten by O2 afterwards.
#define O2_OFF   XQ_OFF   // fp32 8MB, written by fc AFTER fused_attn
#define OBF_OFF  XV_OFF   // bf16 4MB, written by fused_attn

__device__ inline ushort_t f2bf(float x) {
    unsigned u = __builtin_bit_cast(unsigned, x);
    unsigned r = (u + 0x7FFFu + ((u >> 16) & 1u)) >> 16;
    return (ushort_t)r;
}
__device__ inline unsigned pk2(float a, float b) {
    return (unsigned)f2bf(a) | ((unsigned)f2bf(b) << 16);
}

// ---------------------------------------------------------------------------
// Merged setup kernel (R6, unchanged): poscvt (blocks 0..1023) + weight cvt
// (1024..2047) + parallelized prep (block 2048).
// ---------------------------------------------------------------------------
__global__ __launch_bounds__(256)
void setup_kernel(const float* __restrict__ pos,
                  const float* __restrict__ w_qs, const float* __restrict__ w_ks,
                  const float* __restrict__ w_vs, const float* __restrict__ w_fc,
                  const float* __restrict__ rp_w1, const float* __restrict__ rp_b1,
                  const float* __restrict__ rp_w2, const float* __restrict__ rp_b2,
                  unsigned* __restrict__ posbf,
                  ushort_t* __restrict__ WQ, ushort_t* __restrict__ WK,
                  ushort_t* __restrict__ WV, ushort_t* __restrict__ WF,
                  float* __restrict__ ws)
{
    const int bid = blockIdx.x;
    const int tid = threadIdx.x;
    if (bid < 1024) {                       // pos -> packed bf16 pairs
        int t = bid * 256 + tid;
        float4 a = *(const float4*)&pos[t * 8];
        float4 b = *(const float4*)&pos[t * 8 + 4];
        uint4 o = {pk2(a.x, a.y), pk2(a.z, a.w), pk2(b.x, b.y), pk2(b.z, b.w)};
        *(uint4*)&posbf[t * 4] = o;
    } else if (bid < 2048) {                // 4 weight matrices -> bf16
        int which = (bid - 1024) >> 8;
        int t = ((bid - 1024) & 255) * 256 + tid;
        const float* s = (which == 0) ? w_qs : (which == 1) ? w_ks
                       : (which == 2) ? w_vs : w_fc;
        ushort_t* d = (which == 0) ? WQ : (which == 1) ? WK
                    : (which == 2) ? WV : WF;
        float4 v = *(const float4*)&s[t * 4];
        uint2 o = {pk2(v.x, v.y), pk2(v.z, v.w)};
        *(uint2*)&d[t * 4] = o;
    } else {                                // prep: wc[] = rp_w2 @ {rp_b1, rp_w1} + rp_b2
        __shared__ float red[4][64][3];
        int d = tid & 63, p = tid >> 6;
        float w0 = 0.f, w1 = 0.f, cc = 0.f;
        #pragma unroll
        for (int jj = 0; jj < 16; jj++) {
            int j = p * 16 + jj;
            float r2 = rp_w2[d * 64 + j];
            w0 += r2 * rp_w1[j * 2 + 0];
            w1 += r2 * rp_w1[j * 2 + 1];
            cc += r2 * rp_b1[j];
        }
        red[p][d][0] = w0; red[p][d][1] = w1; red[p][d][2] = cc;
        __syncthreads();
        if (p == 0) {
            w0 = red[0][d][0] + red[1][d][0] + red[2][d][0] + red[3][d][0];
            w1 = red[0][d][1] + red[1][d][1] + red[2][d][1] + red[3][d][1];
            cc = red[0][d][2] + red[1][d][2] + red[2][d][2] + red[3][d][2];
            ws[d] = cc + rp_b2[d];
            ws[64 + 2 * d + 0] = w0;
            ws[64 + 2 * d + 1] = w1;
        }
    }
}

// ---------------------------------------------------------------------------
// Q/K/V projection GEMM, R8 rebuild (m93-step of the ladder):
// 128x128 tile, BK=32, 4 waves each owning a 64x64 quadrant (acc[4][4]).
// Per wave per barrier: 16 MFMA + 8 ds_read_b128 (2:1) vs R7's 8 MFMA + 16
// reads — the 64²-tile structure was the m102 N=512 collapse regime (~25 TF).
// Reg-staged dbuf (one barrier/iter), staging set = 24 named VGPRs (R4-safe).
// n-major grid (32,4,3): wgid%8 = n-tile%8 -> o-blocks of an n-tile share XCD.
// Y[n,o] = sum_m X[n,m]*Wt[o,m]; N=4096, O=512, M=512; fp32 X read directly.
// ---------------------------------------------------------------------------
#define AP 40   // LDS row pitch for 32-col tiles (+8 pad, 80B rows)
__global__ __launch_bounds__(256)
void mfma_gemm_qkv(const float* __restrict__ xq, const float* __restrict__ xk,
                   const float* __restrict__ xv,
                   const ushort_t* __restrict__ wq, const ushort_t* __restrict__ wk,
                   const ushort_t* __restrict__ wv,
                   ushort_t* __restrict__ Qbf, ushort_t* __restrict__ Kbf,
                   ushort_t* __restrict__ Vt, const float* __restrict__ wc)
{
    __shared__ ushort_t As[2][128 * AP];    // 2 x 10240 B
    __shared__ ushort_t Bs[2][128 * AP];    // 2 x 10240 B  (total 40 KB)
    const int bz = blockIdx.z;
    const float* X = (bz == 0) ? xq : (bz == 1) ? xk : xv;
    const ushort_t* Wt = (bz == 0) ? wq : (bz == 1) ? wk : wv;
    const int n0 = blockIdx.x * 128;        // n-major: XCD = blockIdx.x % 8
    const int o0 = blockIdx.y * 128;
    const int tid = threadIdx.x;
    const int wave = tid >> 6, lane = tid & 63;
    const int m16 = lane & 15, g = lane >> 4;
    const int wr = wave >> 1, wcol = wave & 1;

    float4 ax[4];                           // staged X (fp32, cvt on store)
    uint4  bx[2];                           // staged W (bf16)

#define LOADA(k0_) { _Pragma("unroll") \
    for (int it = 0; it < 4; it++) { \
        int idx = tid + it * 256; \
        int row = idx >> 3, c4 = (idx & 7) * 4; \
        ax[it] = *(const float4*)&X[(n0 + row) * 512 + (k0_) + c4]; } }
#define LOADB(k0_) { _Pragma("unroll") \
    for (int it = 0; it < 2; it++) { \
        int idx = tid + it * 256; \
        int row = idx >> 2, c8 = (idx & 3) * 8; \
        bx[it] = *(const uint4*)&Wt[(o0 + row) * 512 + (k0_) + c8]; } }
#define STORES(b_) { _Pragma("unroll") \
    for (int it = 0; it < 4; it++) { \
        int idx = tid + it * 256; \
        int row = idx >> 3, c4 = (idx & 7) * 4; \
        uint2 o = {pk2(ax[it].x, ax[it].y), pk2(ax[it].z, ax[it].w)}; \
        *(uint2*)&As[b_][row * AP + c4] = o; } \
    _Pragma("unroll") \
    for (int it = 0; it < 2; it++) { \
        int idx = tid + it * 256; \
        int row = idx >> 2, c8 = (idx & 3) * 8; \
        *(uint4*)&Bs[b_][row * AP + c8] = bx[it]; } }

    f32x4 acc[4][4] = {};
    LOADA(0); LOADB(0); STORES(0);
    __syncthreads();
    int cur = 0;
    for (int k0 = 0; k0 < 512; k0 += 32) {
        if (k0 + 32 < 512) { LOADA(k0 + 32); LOADB(k0 + 32); }
        bf16x8 af[4], bfr[4];
        #pragma unroll
        for (int m = 0; m < 4; m++)
            af[m] = *(const bf16x8*)&As[cur][(wr * 64 + m * 16 + m16) * AP + g * 8];
        #pragma unroll
        for (int t = 0; t < 4; t++)
            bfr[t] = *(const bf16x8*)&Bs[cur][(wcol * 64 + t * 16 + m16) * AP + g * 8];
        #pragma unroll
        for (int m = 0; m < 4; m++)
            #pragma unroll
            for (int t = 0; t < 4; t++)
                acc[m][t] = __builtin_amdgcn_mfma_f32_16x16x32_bf16(af[m], bfr[t], acc[m][t], 0, 0, 0);
        if (k0 + 32 < 512) STORES(cur ^ 1);
        __syncthreads();
        cur ^= 1;
    }
#undef LOADA
#undef LOADB
#undef STORES

    // epilogue: scatter stores (R6 measured LDS-transpose ~ neutral; keep simple)
    #pragma unroll
    for (int m = 0; m < 4; m++) {
        #pragma unroll
        for (int t = 0; t < 4; t++) {
            int o = o0 + wcol * 64 + t * 16 + m16;
            int h = o >> 6, d = o & 63;
            #pragma unroll
            for (int r = 0; r < 4; r++) {
                int n = n0 + wr * 64 + m * 16 + g * 4 + r;
                int b = n >> 10, s = n & 1023;
                float a = acc[m][t][r];
                if (bz == 0) {
                    Qbf[(((b * NHD + h) << 10) + s) * 64 + d] = f2bf(a);
                } else if (bz == 1) {
                    int base = ((((b * NHD + h) << 10) + s) * 192) + d;
                    Kbf[base]       = f2bf(a * wc[d]);
                    Kbf[base + 64]  = f2bf(a * wc[64 + 2 * d + 0]);
                    Kbf[base + 128] = f2bf(a * wc[64 + 2 * d + 1]);
                } else {
                    Vt[((b * NHD + h) * 64 + d) * 1024 + s] = f2bf(a);
                }
            }
        }
    }
}

// ---------------------------------------------------------------------------
// Output-projection GEMM, R8: same 128x128/BK=32 structure; bf16 X (Obf),
// fp32 out + residual. N=4096, O=512, M=512. Grid (32,4) n-major.
// ---------------------------------------------------------------------------
__global__ __launch_bounds__(256)
void mfma_gemm_fc(const ushort_t* __restrict__ X, const ushort_t* __restrict__ Wt,
                  float* __restrict__ ofp, const float* __restrict__ resid)
{
    __shared__ ushort_t As[2][128 * AP];
    __shared__ ushort_t Bs[2][128 * AP];
    const int n0 = blockIdx.x * 128;
    const int o0 = blockIdx.y * 128;
    const int tid = threadIdx.x;
    const int wave = tid >> 6, lane = tid & 63;
    const int m16 = lane & 15, g = lane >> 4;
    const int wr = wave >> 1, wcol = wave & 1;

    uint4 axr[2], bx[2];

#define LOADAF(k0_) { _Pragma("unroll") \
    for (int it = 0; it < 2; it++) { \
        int idx = tid + it * 256; \
        int row = idx >> 2, c8 = (idx & 3) * 8; \
        axr[it] = *(const uint4*)&X[(n0 + row) * 512 + (k0_) + c8]; } }
#define LOADBF(k0_) { _Pragma("unroll") \
    for (int it = 0; it < 2; it++) { \
        int idx = tid + it * 256; \
        int row = idx >> 2, c8 = (idx & 3) * 8; \
        bx[it] = *(const uint4*)&Wt[(o0 + row) * 512 + (k0_) + c8]; } }
#define STORESF(b_) { _Pragma("unroll") \
    for (int it = 0; it < 2; it++) { \
        int idx = tid + it * 256; \
        int row = idx >> 2, c8 = (idx & 3) * 8; \
        *(uint4*)&As[b_][row * AP + c8] = axr[it]; \
        *(uint4*)&Bs[b_][row * AP + c8] = bx[it]; } }

    f32x4 acc[4][4] = {};
    LOADAF(0); LOADBF(0); STORESF(0);
    __syncthreads();
    int cur = 0;
    for (int k0 = 0; k0 < 512; k0 += 32) {
        if (k0 + 32 < 512) { LOADAF(k0 + 32); LOADBF(k0 + 32); }
        bf16x8 af[4], bfr[4];
        #pragma unroll
        for (int m = 0; m < 4; m++)
            af[m] = *(const bf16x8*)&As[cur][(wr * 64 + m * 16 + m16) * AP + g * 8];
        #pragma unroll
        for (int t = 0; t < 4; t++)
            bfr[t] = *(const bf16x8*)&Bs[cur][(wcol * 64 + t * 16 + m16) * AP + g * 8];
        #pragma unroll
        for (int m = 0; m < 4; m++)
            #pragma unroll
            for (int t = 0; t < 4; t++)
                acc[m][t] = __builtin_amdgcn_mfma_f32_16x16x32_bf16(af[m], bfr[t], acc[m][t], 0, 0, 0);
        if (k0 + 32 < 512) STORESF(cur ^ 1);
        __syncthreads();
        cur ^= 1;
    }
#undef LOADAF
#undef LOADBF
#undef STORESF

    #pragma unroll
    for (int m = 0; m < 4; m++) {
        #pragma unroll
        for (int t = 0; t < 4; t++) {
            int o = o0 + wcol * 64 + t * 16 + m16;
            #pragma unroll
            for (int r = 0; r < 4; r++) {
                int n = n0 + wr * 64 + m * 16 + g * 4 + r;
                ofp[n * 512 + o] = acc[m][t][r] + resid[n * 512 + o];
            }
        }
    }
}

// ---------------------------------------------------------------------------
// Fused score + softmax + PV — EXACT R3/R5 version (86-88 µs measured). Ledger:
//   R1: static-max softmax + __expf + Q-in-regs (exposed pos-load latency)
//   R3: pos packed bf16 + staged via LDS coalesced  -> 231 -> 89.4 µs
//   R4: reg-array prefetch -> compiler spill -> 201 µs (REVERTED)
//   R5-R7: frozen, reproduces 86-88 µs. DO NOT TOUCH without A/B guard.
// ---------------------------------------------------------------------------
#define QPITCH 72
#define KPLANE (64 * QPITCH + 8)
#define POSP 68   // uints per pos row: 64 + 4 pad (row pitch 272B, 16B-aligned)
__global__ __launch_bounds__(256)
void fused_attn(const ushort_t* __restrict__ Qbf, const ushort_t* __restrict__ Kbf,
                const unsigned* __restrict__ posu, const ushort_t* __restrict__ Vt,
                float* __restrict__ attn, ushort_t* __restrict__ Obf)
{
    __shared__ ushort_t Ks[3 * KPLANE];      // 27696 B
    __shared__ ushort_t Vs[64 * QPITCH];     //  9216 B
    __shared__ ushort_t Ps[64 * QPITCH];     //  9216 B
    __shared__ unsigned PosS[64 * POSP];     // 17408 B   (total 63536 B)
    const int bh = blockIdx.x;
    const int q0 = blockIdx.y * 64;
    const int tid = threadIdx.x;
    const int wave = tid >> 6, lane = tid & 63;
    const int m16 = lane & 15, g = lane >> 4;

    // Q fragment directly global -> registers (one-time, 16B x2 per thread)
    const ushort_t* qrow = &Qbf[((bh << 10) + q0 + wave * 16 + m16) * 64];
    bf16x8 qf0 = *(const bf16x8*)&qrow[g * 8];
    bf16x8 qf1 = *(const bf16x8*)&qrow[32 + g * 8];

    float l[4] = {0.f, 0.f, 0.f, 0.f};

    // ---------------- pass 1: denominator sum (static max = 0) ----------------
    for (int k0 = 0; k0 < 1024; k0 += 64) {
        #pragma unroll
        for (int it = 0; it < 6; it++) {
            int idx = tid + it * 256;
            int row = idx / 24, c = idx % 24;
            int j = c >> 3, d8 = (c & 7) * 8;
            *(uint4*)&Ks[j * KPLANE + row * QPITCH + d8] =
                *(const uint4*)&Kbf[((bh << 10) + k0 + row) * 192 + c * 8];
        }
        #pragma unroll
        for (int it = 0; it < 4; it++) {
            int idx = tid + it * 256;              // 0..1023
            int row = idx >> 4, c4 = (idx & 15) * 4;
            *(uint4*)&PosS[row * POSP + c4] =
                *(const uint4*)&posu[(q0 + row) * 1024 + k0 + c4];
        }
        __syncthreads();

        f32x4 sc[4][3] = {};
        #pragma unroll
        for (int kc = 0; kc < 2; kc++) {
            bf16x8 af = kc ? qf1 : qf0;
            #pragma unroll
            for (int tk = 0; tk < 4; tk++)
                #pragma unroll
                for (int j = 0; j < 3; j++) {
                    bf16x8 bfv = *(const bf16x8*)&Ks[j * KPLANE + (tk * 16 + m16) * QPITCH + kc * 32 + g * 8];
                    sc[tk][j] = __builtin_amdgcn_mfma_f32_16x16x32_bf16(af, bfv, sc[tk][j], 0, 0, 0);
                }
        }

        #pragma unroll
        for (int r = 0; r < 4; r++) {
            #pragma unroll
            for (int tk = 0; tk < 4; tk++) {
                unsigned pu = PosS[(wave * 16 + g * 4 + r) * POSP + tk * 16 + m16];
                float p0 = __builtin_bit_cast(float, pu << 16);
                float p1 = __builtin_bit_cast(float, pu & 0xFFFF0000u);
                float s = (sc[tk][0][r] + p0 * sc[tk][1][r] + p1 * sc[tk][2][r]) * 0.125f;
                l[r] += __expf(s);
            }
        }
        __syncthreads();
    }
    // single cross-lane reduce (16-lane groups share the same q rows)
    float inv_l[4];
    #pragma unroll
    for (int r = 0; r < 4; r++) {
        float s = l[r];
        #pragma unroll
        for (int msk = 1; msk < 16; msk <<= 1) s += __shfl_xor(s, msk, 64);
        inv_l[r] = 1.0f / s;
    }

    // ---------------- pass 2: probs write + PV ----------------
    f32x4 ao[4] = {};
    for (int k0 = 0; k0 < 1024; k0 += 64) {
        #pragma unroll
        for (int it = 0; it < 6; it++) {
            int idx = tid + it * 256;
            int row = idx / 24, c = idx % 24;
            int j = c >> 3, d8 = (c & 7) * 8;
            *(uint4*)&Ks[j * KPLANE + row * QPITCH + d8] =
                *(const uint4*)&Kbf[((bh << 10) + k0 + row) * 192 + c * 8];
        }
        #pragma unroll
        for (int it = 0; it < 2; it++) {
            int idx = tid + it * 256;
            int row = idx >> 3, c8 = (idx & 7) * 8;
            *(uint4*)&Vs[row * QPITCH + c8] = *(const uint4*)&Vt[(bh * 64 + row) * 1024 + k0 + c8];
        }
        #pragma unroll
        for (int it = 0; it < 4; it++) {
            int idx = tid + it * 256;
            int row = idx >> 4, c4 = (idx & 15) * 4;
            *(uint4*)&PosS[row * POSP + c4] =
                *(const uint4*)&posu[(q0 + row) * 1024 + k0 + c4];
        }
        __syncthreads();

        f32x4 sc[4][3] = {};
        #pragma unroll
        for (int kc = 0; kc < 2; kc++) {
            bf16x8 af = kc ? qf1 : qf0;
            #pragma unroll
            for (int tk = 0; tk < 4; tk++)
                #pragma unroll
                for (int j = 0; j < 3; j++) {
                    bf16x8 bfv = *(const bf16x8*)&Ks[j * KPLANE + (tk * 16 + m16) * QPITCH + kc * 32 + g * 8];
                    sc[tk][j] = __builtin_amdgcn_mfma_f32_16x16x32_bf16(af, bfv, sc[tk][j], 0, 0, 0);
                }
        }

        #pragma unroll
        for (int r = 0; r < 4; r++) {
            int q = q0 + wave * 16 + g * 4 + r;
            #pragma unroll
            for (int tk = 0; tk < 4; tk++) {
                unsigned pu = PosS[(wave * 16 + g * 4 + r) * POSP + tk * 16 + m16];
                float p0 = __builtin_bit_cast(float, pu << 16);
                float p1 = __builtin_bit_cast(float, pu & 0xFFFF0000u);
                float s = (sc[tk][0][r] + p0 * sc[tk][1][r] + p1 * sc[tk][2][r]) * 0.125f;
                float p = __expf(s) * inv_l[r];
                attn[((bh << 10) + q) * 1024 + k0 + tk * 16 + m16] = p;
                Ps[(wave * 16 + g * 4 + r) * QPITCH + tk * 16 + m16] = f2bf(p);
            }
        }
        __syncthreads();

        #pragma unroll
        for (int kc = 0; kc < 2; kc++) {
            bf16x8 a = *(const bf16x8*)&Ps[(wave * 16 + m16) * QPITCH + kc * 32 + g * 8];
            #pragma unroll
            for (int td = 0; td < 4; td++) {
                bf16x8 b = *(const bf16x8*)&Vs[(td * 16 + m16) * QPITCH + kc * 32 + g * 8];
                ao[td] = __builtin_amdgcn_mfma_f32_16x16x32_bf16(a, b, ao[td], 0, 0, 0);
            }
        }
        __syncthreads();
    }

    const int b = bh >> 3, h = bh & 7;
    #pragma unroll
    for (int td = 0; td < 4; td++) {
        int d = td * 16 + m16;
        #pragma unroll
        for (int r = 0; r < 4; r++) {
            int q = q0 + wave * 16 + g * 4 + r;
            Obf[((b << 10) + q) * 512 + h * 64 + d] = f2bf(ao[td][r]);
        }
    }
}

__global__ __launch_bounds__(256)
void ln_kernel(const float* __restrict__ X, const float* __restrict__ g,
               const float* __restrict__ bta, float* __restrict__ out)
{
    const int row = blockIdx.x;
    const int tid = threadIdx.x;
    float2 x = *(const float2*)&X[row * 512 + tid * 2];
    float s  = x.x + x.y;
    float s2 = x.x * x.x + x.y * x.y;
    for (int off = 32; off; off >>= 1) {
        s  += __shfl_down(s, off, 64);
        s2 += __shfl_down(s2, off, 64);
    }
    __shared__ float rs[4], rs2[4];
    __shared__ float mu_s, rstd_s;
    int wave = tid >> 6, lane = tid & 63;
    if (lane == 0) { rs[wave] = s; rs2[wave] = s2; }
    __syncthreads();
    if (tid == 0) {
        float S1 = rs[0] + rs[1] + rs[2] + rs[3];
        float S2 = rs2[0] + rs2[1] + rs2[2] + rs2[3];
        float mu = S1 * (1.0f / 512.0f);
        float var = S2 * (1.0f / 512.0f) - mu * mu;
        mu_s = mu;
        rstd_s = rsqrtf(var + 1e-6f);
    }
    __syncthreads();
    float mu = mu_s, rstd = rstd_s;
    float2 gv = *(const float2*)&g[tid * 2];
    float2 bv = *(const float2*)&bta[tid * 2];
    float2 o;
    o.x = (x.x - mu) * rstd * gv.x + bv.x;
    o.y = (x.y - mu) * rstd * gv.y + bv.y;
    *(float2*)&out[row * 512 + tid * 2] = o;
}

extern "C" void kernel_launch(void* const* d_in, const int* in_sizes, int n_in,
                              void* d_out, int out_size, void* d_ws, size_t ws_size,
                              hipStream_t stream)
{
    const float* q       = (const float*)d_in[0];
    const float* k       = (const float*)d_in[1];
    const float* v       = (const float*)d_in[2];
    const float* pos_mat = (const float*)d_in[3];
    const float* w_qs    = (const float*)d_in[4];
    const float* w_ks    = (const float*)d_in[5];
    const float* w_vs    = (const float*)d_in[6];
    const float* w_fc    = (const float*)d_in[7];
    const float* rp_w1   = (const float*)d_in[8];
    const float* rp_b1   = (const float*)d_in[9];
    const float* rp_w2   = (const float*)d_in[10];
    const float* rp_b2   = (const float*)d_in[11];
    const float* ln_g    = (const float*)d_in[12];
    const float* ln_b    = (const float*)d_in[13];

    char* wsb = (char*)d_ws;
    float*    wc  = (float*)d_ws;
    ushort_t* WQ  = (ushort_t*)(wsb + WQ_OFF);
    ushort_t* WK  = (ushort_t*)(wsb + WK_OFF);
    ushort_t* WV  = (ushort_t*)(wsb + WV_OFF);
    ushort_t* WF  = (ushort_t*)(wsb + WF_OFF);
    ushort_t* Qbf = (ushort_t*)(wsb + QBF_OFF);
    ushort_t* Kbf = (ushort_t*)(wsb + KBF_OFF);
    ushort_t* Vt  = (ushort_t*)(wsb + VT_OFF);
    float*    O2  = (float*)(wsb + O2_OFF);
    ushort_t* Obf = (ushort_t*)(wsb + OBF_OFF);
    unsigned* Pbf = (unsigned*)(wsb + POSBF_OFF);

    float* out  = (float*)d_out;       // final (B,S,512)
    float* attn = out + 2097152;       // (B,H,S,S) probs

    setup_kernel<<<dim3(2049), 256, 0, stream>>>(pos_mat, w_qs, w_ks, w_vs, w_fc,
                                                 rp_w1, rp_b1, rp_w2, rp_b2,
                                                 Pbf, WQ, WK, WV, WF, wc);

    // 128x128 tiles; n-major grid keeps an n-tile's o-blocks on one XCD
    mfma_gemm_qkv<<<dim3(32, 4, 3), 256, 0, stream>>>(q, k, v, WQ, WK, WV,
                                                      Qbf, Kbf, Vt, wc);

    fused_attn<<<dim3(32, 16), 256, 0, stream>>>(Qbf, Kbf, Pbf, Vt, attn, Obf);

    mfma_gemm_fc<<<dim3(32, 4), 256, 0, stream>>>(Obf, WF, O2, q);
    ln_kernel<<<dim3(4096), 256, 0, stream>>>(O2, ln_g, ln_b, out);
}

// Round 10
// 281.853 us; speedup vs baseline: 1.1578x; 1.1578x over previous
//
#include <hip/hip_runtime.h>
#include <math.h>

// Problem constants
#define NB   4
#define SEQ  1024
#define DMOD 512
#define NHD  8
#define DK   64

typedef unsigned short ushort_t;
typedef __attribute__((ext_vector_type(8))) short bf16x8;
typedef __attribute__((ext_vector_type(4))) float f32x4;

// ---------------- workspace layout (bytes) ----------------
#define XQ_OFF   1024
#define XK_OFF   (XQ_OFF + 4194304)
#define XV_OFF   (XK_OFF + 4194304)
#define WQ_OFF   (XV_OFF + 4194304)
#define WK_OFF   (WQ_OFF + 524288)
#define WV_OFF   (WK_OFF + 524288)
#define WF_OFF   (WV_OFF + 524288)
#define QBF_OFF  (WF_OFF + 524288)
#define KBF_OFF  (QBF_OFF + 4194304)
#define VT_OFF   (KBF_OFF + 12582912)
// aliases (stream-ordered safe):
#define POSBF_OFF XQ_OFF  // 4MB packed-bf16 pos; written by setup, read by
                          // fused_attn, overwritten by O2 afterwards.
#define O2_OFF   XQ_OFF   // fp32 8MB, written by fc AFTER fused_attn
#define OBF_OFF  XV_OFF   // bf16 4MB, written by fused_attn

// GEMM structure ledger:
//   R7 (64² tile, n-major XCD grid, reg-dbuf, 512/1536 blocks): total 281.6 BEST
//   R8 (128² tile, 128/384 blocks): fc 142µs @ ~0% all pipes — latency-serialized,
//       1 blk/CU, no TLP. REVERTED. Parallelism > per-block density at this size.

__device__ inline ushort_t f2bf(float x) {
    unsigned u = __builtin_bit_cast(unsigned, x);
    unsigned r = (u + 0x7FFFu + ((u >> 16) & 1u)) >> 16;
    return (ushort_t)r;
}
__device__ inline unsigned pk2(float a, float b) {
    return (unsigned)f2bf(a) | ((unsigned)f2bf(b) << 16);
}

// ---------------------------------------------------------------------------
// Merged setup kernel (R6, unchanged): poscvt (blocks 0..1023) + weight cvt
// (1024..2047) + parallelized prep (block 2048).
// ---------------------------------------------------------------------------
__global__ __launch_bounds__(256)
void setup_kernel(const float* __restrict__ pos,
                  const float* __restrict__ w_qs, const float* __restrict__ w_ks,
                  const float* __restrict__ w_vs, const float* __restrict__ w_fc,
                  const float* __restrict__ rp_w1, const float* __restrict__ rp_b1,
                  const float* __restrict__ rp_w2, const float* __restrict__ rp_b2,
                  unsigned* __restrict__ posbf,
                  ushort_t* __restrict__ WQ, ushort_t* __restrict__ WK,
                  ushort_t* __restrict__ WV, ushort_t* __restrict__ WF,
                  float* __restrict__ ws)
{
    const int bid = blockIdx.x;
    const int tid = threadIdx.x;
    if (bid < 1024) {                       // pos -> packed bf16 pairs
        int t = bid * 256 + tid;
        float4 a = *(const float4*)&pos[t * 8];
        float4 b = *(const float4*)&pos[t * 8 + 4];
        uint4 o = {pk2(a.x, a.y), pk2(a.z, a.w), pk2(b.x, b.y), pk2(b.z, b.w)};
        *(uint4*)&posbf[t * 4] = o;
    } else if (bid < 2048) {                // 4 weight matrices -> bf16
        int which = (bid - 1024) >> 8;
        int t = ((bid - 1024) & 255) * 256 + tid;
        const float* s = (which == 0) ? w_qs : (which == 1) ? w_ks
                       : (which == 2) ? w_vs : w_fc;
        ushort_t* d = (which == 0) ? WQ : (which == 1) ? WK
                    : (which == 2) ? WV : WF;
        float4 v = *(const float4*)&s[t * 4];
        uint2 o = {pk2(v.x, v.y), pk2(v.z, v.w)};
        *(uint2*)&d[t * 4] = o;
    } else {                                // prep: wc[] = rp_w2 @ {rp_b1, rp_w1} + rp_b2
        __shared__ float red[4][64][3];
        int d = tid & 63, p = tid >> 6;
        float w0 = 0.f, w1 = 0.f, cc = 0.f;
        #pragma unroll
        for (int jj = 0; jj < 16; jj++) {
            int j = p * 16 + jj;
            float r2 = rp_w2[d * 64 + j];
            w0 += r2 * rp_w1[j * 2 + 0];
            w1 += r2 * rp_w1[j * 2 + 1];
            cc += r2 * rp_b1[j];
        }
        red[p][d][0] = w0; red[p][d][1] = w1; red[p][d][2] = cc;
        __syncthreads();
        if (p == 0) {
            w0 = red[0][d][0] + red[1][d][0] + red[2][d][0] + red[3][d][0];
            w1 = red[0][d][1] + red[1][d][1] + red[2][d][1] + red[3][d][1];
            cc = red[0][d][2] + red[1][d][2] + red[2][d][2] + red[3][d][2];
            ws[d] = cc + rp_b2[d];
            ws[64 + 2 * d + 0] = w0;
            ws[64 + 2 * d + 1] = w1;
        }
    }
}

#define GP 72

// ---------------------------------------------------------------------------
// Q/K/V projection GEMM — EXACT R7 version (part of the 281.6µs best).
// 64² tile, n-major grid (64,8,3) for XCD L2 sharing, reg-staged dbuf with
// one barrier/iter. DO NOT tile up (R8: 128² collapsed to 1 blk/CU latency).
// ---------------------------------------------------------------------------
__global__ __launch_bounds__(256)
void mfma_gemm_qkv(const float* __restrict__ xq, const float* __restrict__ xk,
                   const float* __restrict__ xv,
                   const ushort_t* __restrict__ wq, const ushort_t* __restrict__ wk,
                   const ushort_t* __restrict__ wv,
                   ushort_t* __restrict__ Qbf, ushort_t* __restrict__ Kbf,
                   ushort_t* __restrict__ Vt, const float* __restrict__ wc)
{
    __shared__ ushort_t SH[18432];          // 36.9KB: {X0,X1,W0,W1} 4608 each; epilogue reuse
    const int bz = blockIdx.z;
    const float* X = (bz == 0) ? xq : (bz == 1) ? xk : xv;
    const ushort_t* Wt = (bz == 0) ? wq : (bz == 1) ? wk : wv;
    const int n0 = blockIdx.x * 64;         // n-major: XCD = blockIdx.x % 8
    const int o0 = blockIdx.y * 64;
    const int tid = threadIdx.x;
    const int wave = tid >> 6, lane = tid & 63;
    const int m16 = lane & 15, g = lane >> 4;
    const int sr = tid >> 3, sc8 = (tid & 7) * 8;   // staging row (0..31), col*8

    float4 xa0, xb0, xa1, xb1;              // staged X (fp32, cvt on store)
    uint4  wr0, wr1;                        // staged W (bf16)

#define LOADT(m0_) { \
    xa0 = *(const float4*)&X[(n0 + sr) * 512 + (m0_) + sc8]; \
    xb0 = *(const float4*)&X[(n0 + sr) * 512 + (m0_) + sc8 + 4]; \
    xa1 = *(const float4*)&X[(n0 + sr + 32) * 512 + (m0_) + sc8]; \
    xb1 = *(const float4*)&X[(n0 + sr + 32) * 512 + (m0_) + sc8 + 4]; \
    wr0 = *(const uint4*)&Wt[(o0 + sr) * 512 + (m0_) + sc8]; \
    wr1 = *(const uint4*)&Wt[(o0 + sr + 32) * 512 + (m0_) + sc8]; }
#define STORET(b_) { \
    ushort_t* Xs_ = SH + (b_) * 4608; \
    ushort_t* Ws_ = SH + 9216 + (b_) * 4608; \
    uint4 ox0 = {pk2(xa0.x, xa0.y), pk2(xa0.z, xa0.w), pk2(xb0.x, xb0.y), pk2(xb0.z, xb0.w)}; \
    uint4 ox1 = {pk2(xa1.x, xa1.y), pk2(xa1.z, xa1.w), pk2(xb1.x, xb1.y), pk2(xb1.z, xb1.w)}; \
    *(uint4*)&Xs_[sr * GP + sc8] = ox0; \
    *(uint4*)&Xs_[(sr + 32) * GP + sc8] = ox1; \
    *(uint4*)&Ws_[sr * GP + sc8] = wr0; \
    *(uint4*)&Ws_[(sr + 32) * GP + sc8] = wr1; }

    f32x4 acc[4] = {};
    LOADT(0); STORET(0);
    __syncthreads();
    int cur = 0;
    for (int m0 = 0; m0 < 512; m0 += 64) {
        const int nxt = m0 + 64;
        if (nxt < 512) LOADT(nxt);
        const ushort_t* Xs = SH + cur * 4608;
        const ushort_t* Ws = SH + 9216 + cur * 4608;
        #pragma unroll
        for (int kc = 0; kc < 2; kc++) {
            bf16x8 a = *(const bf16x8*)&Xs[(wave * 16 + m16) * GP + kc * 32 + g * 8];
            #pragma unroll
            for (int to = 0; to < 4; to++) {
                bf16x8 b = *(const bf16x8*)&Ws[(to * 16 + m16) * GP + kc * 32 + g * 8];
                acc[to] = __builtin_amdgcn_mfma_f32_16x16x32_bf16(a, b, acc[to], 0, 0, 0);
            }
        }
        if (nxt < 512) STORET(cur ^ 1);
        __syncthreads();
        cur ^= 1;
    }
#undef LOADT
#undef STORET

    const int b = n0 >> 10, s0 = n0 & 1023, h = o0 >> 6;
    const int bh = b * NHD + h;
    const int srow = wave * 16 + g * 4;

    if (bz == 0) {
        #pragma unroll
        for (int to = 0; to < 4; to++)
            #pragma unroll
            for (int r = 0; r < 4; r++)
                SH[(srow + r) * GP + to * 16 + m16] = f2bf(acc[to][r]);
        __syncthreads();
        #pragma unroll
        for (int it = 0; it < 2; it++) {
            int cid = tid + it * 256;
            int row = cid >> 3, c8 = (cid & 7) * 8;
            *(uint4*)&Qbf[((bh << 10) + s0 + row) * 64 + c8] =
                *(const uint4*)&SH[row * GP + c8];
        }
    } else if (bz == 1) {
        #pragma unroll
        for (int to = 0; to < 4; to++) {
            int d = to * 16 + m16;
            float c0 = wc[d], c1 = wc[64 + 2 * d], c2 = wc[64 + 2 * d + 1];
            #pragma unroll
            for (int r = 0; r < 4; r++) {
                float a = acc[to][r];
                int rb = (srow + r) * 200 + d;
                SH[rb]       = f2bf(a * c0);
                SH[rb + 64]  = f2bf(a * c1);
                SH[rb + 128] = f2bf(a * c2);
            }
        }
        __syncthreads();
        #pragma unroll
        for (int it = 0; it < 6; it++) {
            int cid = tid + it * 256;
            int row = cid / 24, c = cid % 24;
            *(uint4*)&Kbf[((bh << 10) + s0 + row) * 192 + c * 8] =
                *(const uint4*)&SH[row * 200 + c * 8];
        }
    } else {
        #pragma unroll
        for (int to = 0; to < 4; to++)
            #pragma unroll
            for (int r = 0; r < 4; r++)
                SH[(to * 16 + m16) * GP + srow + r] = f2bf(acc[to][r]);
        __syncthreads();
        #pragma unroll
        for (int it = 0; it < 2; it++) {
            int cid = tid + it * 256;
            int row = cid >> 3, c8 = (cid & 7) * 8;
            *(uint4*)&Vt[(bh * 64 + row) * 1024 + s0 + c8] =
                *(const uint4*)&SH[row * GP + c8];
        }
    }
}

// ---------------------------------------------------------------------------
// Output-projection GEMM — EXACT R7 version. 64² tile, n-major (64,8), dbuf.
// ---------------------------------------------------------------------------
__global__ __launch_bounds__(256)
void mfma_gemm_fc(const ushort_t* __restrict__ X, const ushort_t* __restrict__ Wt,
                  float* __restrict__ ofp, const float* __restrict__ resid)
{
    __shared__ ushort_t SH[18432];
    const int n0 = blockIdx.x * 64;         // n-major
    const int o0 = blockIdx.y * 64;
    const int tid = threadIdx.x;
    const int wave = tid >> 6, lane = tid & 63;
    const int m16 = lane & 15, g = lane >> 4;
    const int sr = tid >> 3, sc8 = (tid & 7) * 8;

    uint4 xr0, xr1, wr0, wr1;

#define LOADF(m0_) { \
    xr0 = *(const uint4*)&X[(n0 + sr) * 512 + (m0_) + sc8]; \
    xr1 = *(const uint4*)&X[(n0 + sr + 32) * 512 + (m0_) + sc8]; \
    wr0 = *(const uint4*)&Wt[(o0 + sr) * 512 + (m0_) + sc8]; \
    wr1 = *(const uint4*)&Wt[(o0 + sr + 32) * 512 + (m0_) + sc8]; }
#define STOREF(b_) { \
    ushort_t* Xs_ = SH + (b_) * 4608; \
    ushort_t* Ws_ = SH + 9216 + (b_) * 4608; \
    *(uint4*)&Xs_[sr * GP + sc8] = xr0; \
    *(uint4*)&Xs_[(sr + 32) * GP + sc8] = xr1; \
    *(uint4*)&Ws_[sr * GP + sc8] = wr0; \
    *(uint4*)&Ws_[(sr + 32) * GP + sc8] = wr1; }

    f32x4 acc[4] = {};
    LOADF(0); STOREF(0);
    __syncthreads();
    int cur = 0;
    for (int m0 = 0; m0 < 512; m0 += 64) {
        const int nxt = m0 + 64;
        if (nxt < 512) LOADF(nxt);
        const ushort_t* Xs = SH + cur * 4608;
        const ushort_t* Ws = SH + 9216 + cur * 4608;
        #pragma unroll
        for (int kc = 0; kc < 2; kc++) {
            bf16x8 a = *(const bf16x8*)&Xs[(wave * 16 + m16) * GP + kc * 32 + g * 8];
            #pragma unroll
            for (int to = 0; to < 4; to++) {
                bf16x8 b = *(const bf16x8*)&Ws[(to * 16 + m16) * GP + kc * 32 + g * 8];
                acc[to] = __builtin_amdgcn_mfma_f32_16x16x32_bf16(a, b, acc[to], 0, 0, 0);
            }
        }
        if (nxt < 512) STOREF(cur ^ 1);
        __syncthreads();
        cur ^= 1;
    }
#undef LOADF
#undef STOREF

    #pragma unroll
    for (int to = 0; to < 4; to++) {
        int o = o0 + to * 16 + m16;
        #pragma unroll
        for (int r = 0; r < 4; r++) {
            int n = n0 + wave * 16 + g * 4 + r;
            ofp[n * 512 + o] = acc[to][r] + resid[n * 512 + o];
        }
    }
}

// ---------------------------------------------------------------------------
// Fused score + softmax + PV — EXACT R3/R5 version (86-88 µs measured). Ledger:
//   R1: static-max softmax + __expf + Q-in-regs (exposed pos-load latency)
//   R3: pos packed bf16 + staged via LDS coalesced  -> 231 -> 89.4 µs
//   R4: reg-array prefetch -> compiler spill -> 201 µs (REVERTED)
//   R5-R8: frozen, reproduces 86-88 µs. DO NOT TOUCH without A/B guard.
// ---------------------------------------------------------------------------
#define QPITCH 72
#define KPLANE (64 * QPITCH + 8)
#define POSP 68   // uints per pos row: 64 + 4 pad (row pitch 272B, 16B-aligned)
__global__ __launch_bounds__(256)
void fused_attn(const ushort_t* __restrict__ Qbf, const ushort_t* __restrict__ Kbf,
                const unsigned* __restrict__ posu, const ushort_t* __restrict__ Vt,
                float* __restrict__ attn, ushort_t* __restrict__ Obf)
{
    __shared__ ushort_t Ks[3 * KPLANE];      // 27696 B
    __shared__ ushort_t Vs[64 * QPITCH];     //  9216 B
    __shared__ ushort_t Ps[64 * QPITCH];     //  9216 B
    __shared__ unsigned PosS[64 * POSP];     // 17408 B   (total 63536 B)
    const int bh = blockIdx.x;
    const int q0 = blockIdx.y * 64;
    const int tid = threadIdx.x;
    const int wave = tid >> 6, lane = tid & 63;
    const int m16 = lane & 15, g = lane >> 4;

    // Q fragment directly global -> registers (one-time, 16B x2 per thread)
    const ushort_t* qrow = &Qbf[((bh << 10) + q0 + wave * 16 + m16) * 64];
    bf16x8 qf0 = *(const bf16x8*)&qrow[g * 8];
    bf16x8 qf1 = *(const bf16x8*)&qrow[32 + g * 8];

    float l[4] = {0.f, 0.f, 0.f, 0.f};

    // ---------------- pass 1: denominator sum (static max = 0) ----------------
    for (int k0 = 0; k0 < 1024; k0 += 64) {
        #pragma unroll
        for (int it = 0; it < 6; it++) {
            int idx = tid + it * 256;
            int row = idx / 24, c = idx % 24;
            int j = c >> 3, d8 = (c & 7) * 8;
            *(uint4*)&Ks[j * KPLANE + row * QPITCH + d8] =
                *(const uint4*)&Kbf[((bh << 10) + k0 + row) * 192 + c * 8];
        }
        #pragma unroll
        for (int it = 0; it < 4; it++) {
            int idx = tid + it * 256;              // 0..1023
            int row = idx >> 4, c4 = (idx & 15) * 4;
            *(uint4*)&PosS[row * POSP + c4] =
                *(const uint4*)&posu[(q0 + row) * 1024 + k0 + c4];
        }
        __syncthreads();

        f32x4 sc[4][3] = {};
        #pragma unroll
        for (int kc = 0; kc < 2; kc++) {
            bf16x8 af = kc ? qf1 : qf0;
            #pragma unroll
            for (int tk = 0; tk < 4; tk++)
                #pragma unroll
                for (int j = 0; j < 3; j++) {
                    bf16x8 bfv = *(const bf16x8*)&Ks[j * KPLANE + (tk * 16 + m16) * QPITCH + kc * 32 + g * 8];
                    sc[tk][j] = __builtin_amdgcn_mfma_f32_16x16x32_bf16(af, bfv, sc[tk][j], 0, 0, 0);
                }
        }

        #pragma unroll
        for (int r = 0; r < 4; r++) {
            #pragma unroll
            for (int tk = 0; tk < 4; tk++) {
                unsigned pu = PosS[(wave * 16 + g * 4 + r) * POSP + tk * 16 + m16];
                float p0 = __builtin_bit_cast(float, pu << 16);
                float p1 = __builtin_bit_cast(float, pu & 0xFFFF0000u);
                float s = (sc[tk][0][r] + p0 * sc[tk][1][r] + p1 * sc[tk][2][r]) * 0.125f;
                l[r] += __expf(s);
            }
        }
        __syncthreads();
    }
    // single cross-lane reduce (16-lane groups share the same q rows)
    float inv_l[4];
    #pragma unroll
    for (int r = 0; r < 4; r++) {
        float s = l[r];
        #pragma unroll
        for (int msk = 1; msk < 16; msk <<= 1) s += __shfl_xor(s, msk, 64);
        inv_l[r] = 1.0f / s;
    }

    // ---------------- pass 2: probs write + PV ----------------
    f32x4 ao[4] = {};
    for (int k0 = 0; k0 < 1024; k0 += 64) {
        #pragma unroll
        for (int it = 0; it < 6; it++) {
            int idx = tid + it * 256;
            int row = idx / 24, c = idx % 24;
            int j = c >> 3, d8 = (c & 7) * 8;
            *(uint4*)&Ks[j * KPLANE + row * QPITCH + d8] =
                *(const uint4*)&Kbf[((bh << 10) + k0 + row) * 192 + c * 8];
        }
        #pragma unroll
        for (int it = 0; it < 2; it++) {
            int idx = tid + it * 256;
            int row = idx >> 3, c8 = (idx & 7) * 8;
            *(uint4*)&Vs[row * QPITCH + c8] = *(const uint4*)&Vt[(bh * 64 + row) * 1024 + k0 + c8];
        }
        #pragma unroll
        for (int it = 0; it < 4; it++) {
            int idx = tid + it * 256;
            int row = idx >> 4, c4 = (idx & 15) * 4;
            *(uint4*)&PosS[row * POSP + c4] =
                *(const uint4*)&posu[(q0 + row) * 1024 + k0 + c4];
        }
        __syncthreads();

        f32x4 sc[4][3] = {};
        #pragma unroll
        for (int kc = 0; kc < 2; kc++) {
            bf16x8 af = kc ? qf1 : qf0;
            #pragma unroll
            for (int tk = 0; tk < 4; tk++)
                #pragma unroll
                for (int j = 0; j < 3; j++) {
                    bf16x8 bfv = *(const bf16x8*)&Ks[j * KPLANE + (tk * 16 + m16) * QPITCH + kc * 32 + g * 8];
                    sc[tk][j] = __builtin_amdgcn_mfma_f32_16x16x32_bf16(af, bfv, sc[tk][j], 0, 0, 0);
                }
        }

        #pragma unroll
        for (int r = 0; r < 4; r++) {
            int q = q0 + wave * 16 + g * 4 + r;
            #pragma unroll
            for (int tk = 0; tk < 4; tk++) {
                unsigned pu = PosS[(wave * 16 + g * 4 + r) * POSP + tk * 16 + m16];
                float p0 = __builtin_bit_cast(float, pu << 16);
                float p1 = __builtin_bit_cast(float, pu & 0xFFFF0000u);
                float s = (sc[tk][0][r] + p0 * sc[tk][1][r] + p1 * sc[tk][2][r]) * 0.125f;
                float p = __expf(s) * inv_l[r];
                attn[((bh << 10) + q) * 1024 + k0 + tk * 16 + m16] = p;
                Ps[(wave * 16 + g * 4 + r) * QPITCH + tk * 16 + m16] = f2bf(p);
            }
        }
        __syncthreads();

        #pragma unroll
        for (int kc = 0; kc < 2; kc++) {
            bf16x8 a = *(const bf16x8*)&Ps[(wave * 16 + m16) * QPITCH + kc * 32 + g * 8];
            #pragma unroll
            for (int td = 0; td < 4; td++) {
                bf16x8 b = *(const bf16x8*)&Vs[(td * 16 + m16) * QPITCH + kc * 32 + g * 8];
                ao[td] = __builtin_amdgcn_mfma_f32_16x16x32_bf16(a, b, ao[td], 0, 0, 0);
            }
        }
        __syncthreads();
    }

    const int b = bh >> 3, h = bh & 7;
    #pragma unroll
    for (int td = 0; td < 4; td++) {
        int d = td * 16 + m16;
        #pragma unroll
        for (int r = 0; r < 4; r++) {
            int q = q0 + wave * 16 + g * 4 + r;
            Obf[((b << 10) + q) * 512 + h * 64 + d] = f2bf(ao[td][r]);
        }
    }
}

// ---------------------------------------------------------------------------
// LayerNorm, R9 rewrite: wave-per-row (4 rows/block, grid 1024). float4 loads,
// pure shfl_xor reduce — no LDS, no barriers (was: 4096 blocks, LDS + 2
// barriers each). Numerically identical (same sum order class, fp32).
// ---------------------------------------------------------------------------
__global__ __launch_bounds__(256)
void ln_kernel(const float* __restrict__ X, const float* __restrict__ g,
               const float* __restrict__ bta, float* __restrict__ out)
{
    const int wave = threadIdx.x >> 6, lane = threadIdx.x & 63;
    const int row = blockIdx.x * 4 + wave;
    const int base = row * 512 + lane * 8;
    float4 x0 = *(const float4*)&X[base];
    float4 x1 = *(const float4*)&X[base + 4];
    float s  = x0.x + x0.y + x0.z + x0.w + x1.x + x1.y + x1.z + x1.w;
    float s2 = x0.x * x0.x + x0.y * x0.y + x0.z * x0.z + x0.w * x0.w
             + x1.x * x1.x + x1.y * x1.y + x1.z * x1.z + x1.w * x1.w;
    #pragma unroll
    for (int m = 1; m < 64; m <<= 1) {
        s  += __shfl_xor(s, m, 64);
        s2 += __shfl_xor(s2, m, 64);
    }
    float mu = s * (1.0f / 512.0f);
    float rstd = rsqrtf(s2 * (1.0f / 512.0f) - mu * mu + 1e-6f);
    float4 g0 = *(const float4*)&g[lane * 8];
    float4 g1 = *(const float4*)&g[lane * 8 + 4];
    float4 b0 = *(const float4*)&bta[lane * 8];
    float4 b1 = *(const float4*)&bta[lane * 8 + 4];
    float4 o0, o1;
    o0.x = (x0.x - mu) * rstd * g0.x + b0.x;
    o0.y = (x0.y - mu) * rstd * g0.y + b0.y;
    o0.z = (x0.z - mu) * rstd * g0.z + b0.z;
    o0.w = (x0.w - mu) * rstd * g0.w + b0.w;
    o1.x = (x1.x - mu) * rstd * g1.x + b1.x;
    o1.y = (x1.y - mu) * rstd * g1.y + b1.y;
    o1.z = (x1.z - mu) * rstd * g1.z + b1.z;
    o1.w = (x1.w - mu) * rstd * g1.w + b1.w;
    *(float4*)&out[base] = o0;
    *(float4*)&out[base + 4] = o1;
}

extern "C" void kernel_launch(void* const* d_in, const int* in_sizes, int n_in,
                              void* d_out, int out_size, void* d_ws, size_t ws_size,
                              hipStream_t stream)
{
    const float* q       = (const float*)d_in[0];
    const float* k       = (const float*)d_in[1];
    const float* v       = (const float*)d_in[2];
    const float* pos_mat = (const float*)d_in[3];
    const float* w_qs    = (const float*)d_in[4];
    const float* w_ks    = (const float*)d_in[5];
    const float* w_vs    = (const float*)d_in[6];
    const float* w_fc    = (const float*)d_in[7];
    const float* rp_w1   = (const float*)d_in[8];
    const float* rp_b1   = (const float*)d_in[9];
    const float* rp_w2   = (const float*)d_in[10];
    const float* rp_b2   = (const float*)d_in[11];
    const float* ln_g    = (const float*)d_in[12];
    const float* ln_b    = (const float*)d_in[13];

    char* wsb = (char*)d_ws;
    float*    wc  = (float*)d_ws;
    ushort_t* WQ  = (ushort_t*)(wsb + WQ_OFF);
    ushort_t* WK  = (ushort_t*)(wsb + WK_OFF);
    ushort_t* WV  = (ushort_t*)(wsb + WV_OFF);
    ushort_t* WF  = (ushort_t*)(wsb + WF_OFF);
    ushort_t* Qbf = (ushort_t*)(wsb + QBF_OFF);
    ushort_t* Kbf = (ushort_t*)(wsb + KBF_OFF);
    ushort_t* Vt  = (ushort_t*)(wsb + VT_OFF);
    float*    O2  = (float*)(wsb + O2_OFF);
    ushort_t* Obf = (ushort_t*)(wsb + OBF_OFF);
    unsigned* Pbf = (unsigned*)(wsb + POSBF_OFF);

    float* out  = (float*)d_out;       // final (B,S,512)
    float* attn = out + 2097152;       // (B,H,S,S) probs

    setup_kernel<<<dim3(2049), 256, 0, stream>>>(pos_mat, w_qs, w_ks, w_vs, w_fc,
                                                 rp_w1, rp_b1, rp_w2, rp_b2,
                                                 Pbf, WQ, WK, WV, WF, wc);

    // n-major grid: all o-blocks of an n-tile share an XCD (X slice 1 fetch/XCD)
    mfma_gemm_qkv<<<dim3(64, 8, 3), 256, 0, stream>>>(q, k, v, WQ, WK, WV,
                                                      Qbf, Kbf, Vt, wc);

    fused_attn<<<dim3(32, 16), 256, 0, stream>>>(Qbf, Kbf, Pbf, Vt, attn, Obf);

    mfma_gemm_fc<<<dim3(64, 8), 256, 0, stream>>>(Obf, WF, O2, q);
    ln_kernel<<<dim3(1024), 256, 0, stream>>>(O2, ln_g, ln_b, out);
}